// Round 2
// baseline (968.997 us; speedup 1.0000x reference)
//
#include <hip/hip_runtime.h>

#define NNZC   1000000
#define NPOI   100000
#define NEDGE  50000
#define NUSER  50000
#define DIM    128
#define NL     3

static inline int ceil_div(int a, int b) { return (a + b - 1) / b; }

typedef unsigned int uint32;

// ---- bf16 helpers: rows stored as packed pairs (uint32 = 2 bf16, little-endian) ----
__device__ __forceinline__ float bfLO(uint32 u) { return __uint_as_float(u << 16); }
__device__ __forceinline__ float bfHI(uint32 u) { return __uint_as_float(u & 0xffff0000u); }
__device__ __forceinline__ uint32 bf16_rne(float f) {
    uint32 u = __float_as_uint(f);
    return (u + 0x7fffu + ((u >> 16) & 1u)) >> 16;
}
__device__ __forceinline__ uint32 bfPACK(float a, float b) {
    return bf16_rne(a) | (bf16_rne(b) << 16);
}
// ---- packed ELL entry: vals uniform [0,1) -> sign bit 0 -> 15-bit bf16; col fits 17 bits.
__device__ __forceinline__ uint32 csrPACK(int col, float val) {
    return ((uint32)col) | (bf16_rne(val) << 17);
}
__device__ __forceinline__ int   csrCOL(uint32 e) { return (int)(e & 0x1FFFFu); }
__device__ __forceinline__ float csrVAL(uint32 e) { return __uint_as_float((e >> 17) << 16); }

// per-matrix constants: tar(0), src(1), up(2), pu(3)
__device__ __constant__ const int c_nrows[4]  = { NEDGE, NPOI, NUSER, NPOI };
__device__ __constant__ const int c_cntoff[4] = { 0, NEDGE, NEDGE + NPOI, NEDGE + NPOI + NUSER };
__device__ __constant__ const int c_cap[4]    = { 64, 48, 64, 48 };
__device__ __constant__ const long long c_elloff[4] = { 0, 3200000, 8000000, 11200000 };
// total ELL entries = 16,000,000 (64 MB)

// All sparse-input pointers bundled so fill work can ride along in any launch.
struct FillArgs {
    const int*   r[4];
    const int*   c[4];
    const float* v[4];
    int*    counts;   // counts_all base
    uint32* ell;      // ell base
};

// One "fill unit" = (mtx, z-slice, x-stripe). 512 units per matrix:
//   u>>9 = mtx, (u>>6)&7 = z (row range slice), u&63 = x stripe over NNZ.
// Identical iteration mapping to the dim3(64,4,8) fillE of the 916us baseline
// (z-slicing beat flat fill and x&7 swizzle; keep it).
__device__ __forceinline__ void fill_unit(const FillArgs& fa, int u) {
    int mtx = u >> 9;
    int z   = (u >> 6) & 7;
    int xu  = u & 63;
    int n   = c_nrows[mtx];
    int cap = c_cap[mtx];
    int rlo = (int)(((long long)n * z) >> 3);
    int rhi = (int)(((long long)n * (z + 1)) >> 3);
    const int*   r = fa.r[mtx];
    const int*   c = fa.c[mtx];
    const float* v = fa.v[mtx];
    int*    counts = fa.counts + c_cntoff[mtx];
    uint32* ebase  = fa.ell + c_elloff[mtx];
    int tid = (int)threadIdx.x;
    for (int i = xu * 256 + tid; i < NNZC; i += 16384) {
        int row = r[i];
        if (row >= rlo && row < rhi) {
            int pos = atomicAdd(&counts[row], 1);
            ebase[(size_t)row * cap + pos] = csrPACK(c[i], v[i]);
        }
    }
}

// ---------------- L1 hybrid: fill(tar units 0..511) || bf16 cast of pois || softmax ----------------
__global__ __launch_bounds__(256) void fill_cast_kernel(
    FillArgs fa, const float* __restrict__ pois, uint32* __restrict__ poisbf,
    const float* __restrict__ adi, const float* __restrict__ amv, float* __restrict__ w) {
    int bx = (int)blockIdx.x;
    if (bx < 512) { fill_unit(fa, bx); return; }
    bx -= 512;
    if (bx < 25000) {
        int i = bx * 256 + (int)threadIdx.x;  // 25000*256 == NPOI*64 exactly, no bound check
        float2 f = *(const float2*)(pois + (size_t)i * 2);
        poisbf[i] = bfPACK(f.x, f.y);
        return;
    }
    // last block: softmax over the two 4-element attention vectors
    if (threadIdx.x == 0) {
        for (int b = 0; b < 2; b++) {
            const float* a = b ? amv : adi;
            float m = a[0];
            for (int l = 1; l < 4; l++) m = fmaxf(m, a[l]);
            float e[4]; float s = 0.f;
            for (int l = 0; l < 4; l++) { e[l] = __expf(a[l] - m); s += e[l]; }
            for (int l = 0; l < 4; l++) w[b * 4 + l] = e[l] / s;
        }
    }
}

// ---------------- hop1 SpMM (+ optional embedded fill units [ulo,uhi)) ----------------
template<int CAP>
__global__ __launch_bounds__(256) void spmm1_kernel(
    const int* __restrict__ counts, const uint32* __restrict__ ell,
    const uint32* __restrict__ xbf, uint32* __restrict__ ybf, int n_rows,
    FillArgs fa, int ulo, int uhi) {
    int nf = uhi - ulo;
    if ((int)blockIdx.x < nf) { fill_unit(fa, ulo + (int)blockIdx.x); return; }
    int row = (((int)blockIdx.x - nf) * 256 + (int)threadIdx.x) >> 6;
    int lane = threadIdx.x & 63;
    if (row >= n_rows) return;
    int cnt = counts[row];
    // lanes >= cnt load garbage entries but they are never broadcast
    uint32 e = ell[(size_t)row * CAP + lane];
    float2 acc = make_float2(0.f, 0.f);
    int j = 0;
    for (; j + 4 <= cnt; j += 4) {
        uint32 ea = __shfl(e, j),     eb = __shfl(e, j + 1);
        uint32 ec = __shfl(e, j + 2), ed = __shfl(e, j + 3);
        uint32 ua = xbf[(size_t)csrCOL(ea) * 64 + lane];
        uint32 ub = xbf[(size_t)csrCOL(eb) * 64 + lane];
        uint32 uc = xbf[(size_t)csrCOL(ec) * 64 + lane];
        uint32 ud = xbf[(size_t)csrCOL(ed) * 64 + lane];
        float va = csrVAL(ea), vb = csrVAL(eb), vc = csrVAL(ec), vd = csrVAL(ed);
        acc.x = fmaf(va, bfLO(ua), acc.x); acc.y = fmaf(va, bfHI(ua), acc.y);
        acc.x = fmaf(vb, bfLO(ub), acc.x); acc.y = fmaf(vb, bfHI(ub), acc.y);
        acc.x = fmaf(vc, bfLO(uc), acc.x); acc.y = fmaf(vc, bfHI(uc), acc.y);
        acc.x = fmaf(vd, bfLO(ud), acc.x); acc.y = fmaf(vd, bfHI(ud), acc.y);
    }
    for (; j < cnt; j++) {
        uint32 ej = __shfl(e, j);
        uint32 u = xbf[(size_t)csrCOL(ej) * 64 + lane];
        float vj = csrVAL(ej);
        acc.x = fmaf(vj, bfLO(u), acc.x);
        acc.y = fmaf(vj, bfHI(u), acc.y);
    }
    ybf[(size_t)row * 64 + lane] = bfPACK(acc.x, acc.y);
}

// ---------------- hop2: xnew = relu(A@m)+xin (+ optional embedded fill units) ----------------
template<int CAP>
__global__ __launch_bounds__(256) void spmm2_kernel(
    const int* __restrict__ counts, const uint32* __restrict__ ell,
    const uint32* __restrict__ mbf, const uint32* __restrict__ xinbf,
    uint32* __restrict__ xoutbf, int n_rows,
    FillArgs fa, int ulo, int uhi) {
    int nf = uhi - ulo;
    if ((int)blockIdx.x < nf) { fill_unit(fa, ulo + (int)blockIdx.x); return; }
    int row = (((int)blockIdx.x - nf) * 256 + (int)threadIdx.x) >> 6;
    int lane = threadIdx.x & 63;
    if (row >= n_rows) return;
    int cnt = counts[row];
    uint32 e = ell[(size_t)row * CAP + lane];
    float2 acc = make_float2(0.f, 0.f);
    int j = 0;
    for (; j + 4 <= cnt; j += 4) {
        uint32 ea = __shfl(e, j),     eb = __shfl(e, j + 1);
        uint32 ec = __shfl(e, j + 2), ed = __shfl(e, j + 3);
        uint32 ua = mbf[(size_t)csrCOL(ea) * 64 + lane];
        uint32 ub = mbf[(size_t)csrCOL(eb) * 64 + lane];
        uint32 uc = mbf[(size_t)csrCOL(ec) * 64 + lane];
        uint32 ud = mbf[(size_t)csrCOL(ed) * 64 + lane];
        float va = csrVAL(ea), vb = csrVAL(eb), vc = csrVAL(ec), vd = csrVAL(ed);
        acc.x = fmaf(va, bfLO(ua), acc.x); acc.y = fmaf(va, bfHI(ua), acc.y);
        acc.x = fmaf(vb, bfLO(ub), acc.x); acc.y = fmaf(vb, bfHI(ub), acc.y);
        acc.x = fmaf(vc, bfLO(uc), acc.x); acc.y = fmaf(vc, bfHI(uc), acc.y);
        acc.x = fmaf(vd, bfLO(ud), acc.x); acc.y = fmaf(vd, bfHI(ud), acc.y);
    }
    for (; j < cnt; j++) {
        uint32 ej = __shfl(e, j);
        uint32 u = mbf[(size_t)csrCOL(ej) * 64 + lane];
        float vj = csrVAL(ej);
        acc.x = fmaf(vj, bfLO(u), acc.x);
        acc.y = fmaf(vj, bfHI(u), acc.y);
    }
    size_t o32 = (size_t)row * 64 + lane;
    uint32 ui = xinbf[o32];
    float xn0 = fmaxf(acc.x, 0.f) + bfLO(ui);
    float xn1 = fmaxf(acc.y, 0.f) + bfHI(ui);
    xoutbf[o32] = bfPACK(xn0, xn1);
}

// ---------------- epilogues: out = (w0di+w0mv)*pois + sum_l w_l * x_l ----------------
__global__ void epi1_kernel(const float* __restrict__ pois,
                            const uint32* __restrict__ x1, const uint32* __restrict__ x2,
                            const uint32* __restrict__ x3, const float* __restrict__ w,
                            float* __restrict__ out) {
    int i = blockIdx.x * blockDim.x + threadIdx.x;
    if (i < NPOI * 64) {
        float w0 = w[0] + w[4];
        float2 pf = ((const float2*)pois)[i];
        uint32 u1 = x1[i], u2 = x2[i], u3 = x3[i];
        float o0 = w0 * pf.x + w[1] * bfLO(u1) + w[2] * bfLO(u2) + w[3] * bfLO(u3);
        float o1 = w0 * pf.y + w[1] * bfHI(u1) + w[2] * bfHI(u2) + w[3] * bfHI(u3);
        ((float2*)out)[i] = make_float2(o0, o1);
    }
}

__global__ void epi2_kernel(const uint32* __restrict__ x1, const uint32* __restrict__ x2,
                            const uint32* __restrict__ x3, const float* __restrict__ w,
                            float* __restrict__ out) {
    int i = blockIdx.x * blockDim.x + threadIdx.x;
    if (i < NPOI * 64) {
        uint32 u1 = x1[i], u2 = x2[i], u3 = x3[i];
        float2 ov = ((float2*)out)[i];
        ov.x += w[5] * bfLO(u1) + w[6] * bfLO(u2) + w[7] * bfLO(u3);
        ov.y += w[5] * bfHI(u1) + w[6] * bfHI(u2) + w[7] * bfHI(u3);
        ((float2*)out)[i] = ov;
    }
}

extern "C" void kernel_launch(void* const* d_in, const int* in_sizes, int n_in,
                              void* d_out, int out_size, void* d_ws, size_t ws_size,
                              hipStream_t stream) {
    const float* pois = (const float*)d_in[0];
    const int*   rows_in[4] = { (const int*)d_in[1], (const int*)d_in[4],
                                (const int*)d_in[7], (const int*)d_in[10] };
    const int*   cols_in[4] = { (const int*)d_in[2], (const int*)d_in[5],
                                (const int*)d_in[8], (const int*)d_in[11] };
    const float* vals_in[4] = { (const float*)d_in[3], (const float*)d_in[6],
                                (const float*)d_in[9], (const float*)d_in[12] };
    const float* attn_di = (const float*)d_in[13];
    const float* attn_mv = (const float*)d_in[14];
    float* out = (float*)d_out;

    const int NTOT = NEDGE + NPOI + NUSER + NPOI;  // 300000
    const int cnt_off[4] = { 0, NEDGE, NEDGE + NPOI, NEDGE + NPOI + NUSER };
    const long long ell_off[4] = { 0, 3200000, 8000000, 11200000 };

    // -------- workspace carve-up (~180 MB) --------
    char* p = (char*)d_ws;
    float*  wsoft      = (float*)p;  p += 256;
    int*    counts_all = (int*)p;    p += (size_t)NTOT * 4;
    p = (char*)(((size_t)p + 255) & ~255ull);
    uint32* ell        = (uint32*)p; p += (size_t)16000000 * 4;     // 64 MB ELL
    uint32* mbf        = (uint32*)p; p += (size_t)NEDGE * 64 * 4;   // 12.8 MB
    uint32* poisbf     = (uint32*)p; p += (size_t)NPOI * 64 * 4;    // 25.6 MB
    uint32* xl[3];
    for (int l = 0; l < 3; l++) { xl[l] = (uint32*)p; p += (size_t)NPOI * 64 * 4; }
    (void)ws_size; (void)out_size; (void)n_in; (void)in_sizes;

    FillArgs fa;
    for (int m = 0; m < 4; m++) {
        fa.r[m] = rows_in[m]; fa.c[m] = cols_in[m]; fa.v[m] = vals_in[m];
    }
    fa.counts = counts_all;
    fa.ell = ell;

    hipMemsetAsync(counts_all, 0, (size_t)NTOT * 4, stream);

    // L1: fill(tar) || cast(pois->bf16) || softmax.  tar = units [0,512)
    fill_cast_kernel<<<512 + 25000 + 1, 256, 0, stream>>>(
        fa, pois, poisbf, attn_di, attn_mv, wsoft);

    // Fill-unit schedule: src = units [512,1024) rides with spmm1-L1 (src first
    // needed by spmm2-L1, one launch later).  up/pu = units [1024,2048) spread in
    // 5 chunks across the remaining branch-0 spmm launches (first needed by branch 1).
    const int s1lo[3] = {  512, 1229, 1639 };
    const int s1hi[3] = { 1024, 1434, 1844 };
    const int s2lo[3] = { 1024, 1434, 1844 };
    const int s2hi[3] = { 1229, 1639, 2048 };

    // -------- two branches, 3 layers each; epilogue per branch --------
    for (int br = 0; br < 2; br++) {
        int m1i = br ? 2 : 0;   // up  : tar   (50k rows, CAP 64)
        int m2i = br ? 3 : 1;   // pu  : src   (100k rows, CAP 48)
        const int* cn1 = counts_all + cnt_off[m1i];
        const int* cn2 = counts_all + cnt_off[m2i];
        const uint32* el1 = ell + ell_off[m1i];
        const uint32* el2 = ell + ell_off[m2i];
        const int n1 = 50000;  // NEDGE == NUSER
        const uint32* xcur = poisbf;
        for (int l = 1; l <= NL; l++) {
            int u1lo = br ? 0 : s1lo[l - 1], u1hi = br ? 0 : s1hi[l - 1];
            int u2lo = br ? 0 : s2lo[l - 1], u2hi = br ? 0 : s2hi[l - 1];
            spmm1_kernel<64><<<(u1hi - u1lo) + ceil_div(n1, 4), 256, 0, stream>>>(
                cn1, el1, xcur, mbf, n1, fa, u1lo, u1hi);
            spmm2_kernel<48><<<(u2hi - u2lo) + ceil_div(NPOI, 4), 256, 0, stream>>>(
                cn2, el2, mbf, xcur, xl[l - 1], NPOI, fa, u2lo, u2hi);
            xcur = xl[l - 1];
        }
        if (br == 0)
            epi1_kernel<<<ceil_div(NPOI * 64, 256), 256, 0, stream>>>(
                pois, xl[0], xl[1], xl[2], wsoft, out);
        else
            epi2_kernel<<<ceil_div(NPOI * 64, 256), 256, 0, stream>>>(
                xl[0], xl[1], xl[2], wsoft, out);
    }
}

// Round 3
// 853.562 us; speedup vs baseline: 1.1352x; 1.1352x over previous
//
#include <hip/hip_runtime.h>

#define NNZC   1000000
#define NPOI   100000
#define NEDGE  50000
#define NUSER  50000
#define DIM    128
#define NL     3

#define PB     64          // chunks per matrix for hist/scatter passes (NNZC/PB = 15625)
#define NBKT   196         // row-buckets per matrix (rows>>shift, shift 8 or 9 -> max bucket 195)
#define SCANN  (4 * NBKT * PB)   // 50176 counters (+1 sentinel)

static inline int ceil_div(int a, int b) { return (a + b - 1) / b; }

typedef unsigned int uint32;

// ---- bf16 helpers: rows stored as packed pairs (uint32 = 2 bf16, little-endian) ----
__device__ __forceinline__ float bfLO(uint32 u) { return __uint_as_float(u << 16); }
__device__ __forceinline__ float bfHI(uint32 u) { return __uint_as_float(u & 0xffff0000u); }
__device__ __forceinline__ uint32 bf16_rne(float f) {
    uint32 u = __float_as_uint(f);
    return (u + 0x7fffu + ((u >> 16) & 1u)) >> 16;
}
__device__ __forceinline__ uint32 bfPACK(float a, float b) {
    return bf16_rne(a) | (bf16_rne(b) << 16);
}
// ---- packed ELL entry: vals uniform [0,1) -> sign bit 0 -> 15-bit bf16; col fits 17 bits.
__device__ __forceinline__ uint32 csrPACK(int col, float val) {
    return ((uint32)col) | (bf16_rne(val) << 17);
}
__device__ __forceinline__ int   csrCOL(uint32 e) { return (int)(e & 0x1FFFFu); }
__device__ __forceinline__ float csrVAL(uint32 e) { return __uint_as_float((e >> 17) << 16); }

// per-matrix constants: tar(0), src(1), up(2), pu(3)
__device__ __constant__ const int c_nrows[4]  = { NEDGE, NPOI, NUSER, NPOI };
__device__ __constant__ const int c_cntoff[4] = { 0, NEDGE, NEDGE + NPOI, NEDGE + NPOI + NUSER };
__device__ __constant__ const int c_cap[4]    = { 64, 48, 64, 48 };
__device__ __constant__ const int c_shift[4]  = { 8, 9, 8, 9 };   // rows-per-bucket 256 / 512
__device__ __constant__ const long long c_elloff[4] = { 0, 3200000, 8000000, 11200000 };
// total ELL entries = 16,000,000 (64 MB)

// =============== ELL build: bucketed counting sort (4 passes, no global atomics) ===============

// Pass H: per-(matrix, chunk) histogram over row-buckets.  histG[(m*NBKT+b)*PB + p]
__global__ __launch_bounds__(256) void histH_kernel(
    const int* __restrict__ r0, const int* __restrict__ r1,
    const int* __restrict__ r2, const int* __restrict__ r3,
    int* __restrict__ histG) {
    __shared__ int h[NBKT];
    int m = blockIdx.y, p = blockIdx.x;
    for (int i = threadIdx.x; i < NBKT; i += 256) h[i] = 0;
    __syncthreads();
    const int* r = (m == 0) ? r0 : (m == 1) ? r1 : (m == 2) ? r2 : r3;
    int shift = c_shift[m];
    int lo = p * (NNZC / PB), hi = lo + NNZC / PB;
    for (int i = lo + (int)threadIdx.x; i < hi; i += 256)
        atomicAdd(&h[r[i] >> shift], 1);
    __syncthreads();
    for (int b = threadIdx.x; b < NBKT; b += 256)
        histG[(m * NBKT + b) * PB + p] = h[b];
}

// Pass X: in-place exclusive scan of the 50176 counters (+ sentinel total at [SCANN]).
__global__ __launch_bounds__(256) void scan_kernel(int* __restrict__ g) {
    __shared__ int base[257];
    int t = threadIdx.x;
    const int chunk = SCANN / 256;   // 196
    int lo = t * chunk;
    int s = 0;
    for (int i = 0; i < chunk; i++) s += g[lo + i];
    base[t + 1] = s;
    __syncthreads();
    if (t == 0) {
        base[0] = 0;
        for (int i = 1; i <= 256; i++) base[i] += base[i - 1];
    }
    __syncthreads();
    int off = base[t];
    for (int i = 0; i < chunk; i++) { int v = g[lo + i]; g[lo + i] = off; off += v; }
    if (t == 255) g[SCANN] = base[256];
}

// Pass S: scatter (row, packed entry) records into exclusive dense ranges (bucket-major).
// Each block owns range [scan[(m,b,p)], +hist) per bucket -> LDS cursors, no global atomics.
__global__ __launch_bounds__(256) void scatS_kernel(
    const int* __restrict__ r0, const int* __restrict__ r1,
    const int* __restrict__ r2, const int* __restrict__ r3,
    const int* __restrict__ c0, const int* __restrict__ c1,
    const int* __restrict__ c2, const int* __restrict__ c3,
    const float* __restrict__ v0, const float* __restrict__ v1,
    const float* __restrict__ v2, const float* __restrict__ v3,
    const int* __restrict__ scanG, uint2* __restrict__ rec) {
    __shared__ int cur[NBKT];
    int m = blockIdx.y, p = blockIdx.x;
    for (int b = threadIdx.x; b < NBKT; b += 256)
        cur[b] = scanG[(m * NBKT + b) * PB + p];
    __syncthreads();
    const int*   r = (m == 0) ? r0 : (m == 1) ? r1 : (m == 2) ? r2 : r3;
    const int*   c = (m == 0) ? c0 : (m == 1) ? c1 : (m == 2) ? c2 : c3;
    const float* v = (m == 0) ? v0 : (m == 1) ? v1 : (m == 2) ? v2 : v3;
    int shift = c_shift[m];
    int lo = p * (NNZC / PB), hi = lo + NNZC / PB;
    for (int i = lo + (int)threadIdx.x; i < hi; i += 256) {
        int row = r[i];
        int pos = atomicAdd(&cur[row >> shift], 1);
        rec[pos] = make_uint2((uint32)row, csrPACK(c[i], v[i]));
    }
}

// Pass B: one block per (matrix, bucket).  Bucket rows are block-exclusive -> LDS row
// counters (no global atomics, no counts memset); ELL scatter confined to a 64-96 KB
// L2-resident region so lines fill before eviction.
__global__ __launch_bounds__(256) void fillB_kernel(
    const int* __restrict__ scanG, const uint2* __restrict__ rec,
    int* __restrict__ counts_all, uint32* __restrict__ ell) {
    __shared__ int cnt[512];
    int bx = (int)blockIdx.x;
    int m = bx / NBKT, b = bx - m * NBKT;
    int shift = c_shift[m];
    int rowlo = b << shift;
    int bklen = 1 << shift;
    for (int i = threadIdx.x; i < bklen; i += 256) cnt[i] = 0;
    __syncthreads();
    int lo = scanG[(m * NBKT + b) * PB];
    int hi = scanG[(m * NBKT + b + 1) * PB];   // b=195,m=3 -> scanG[SCANN] sentinel
    int cap = c_cap[m];
    uint32* ebase = ell + c_elloff[m];
    for (int i = lo + (int)threadIdx.x; i < hi; i += 256) {
        uint2 e = rec[i];
        int row = (int)e.x;
        int pos = atomicAdd(&cnt[row - rowlo], 1);
        ebase[(size_t)row * cap + pos] = e.y;
    }
    __syncthreads();
    int nrows_b = c_nrows[m] - rowlo;
    if (nrows_b > bklen) nrows_b = bklen;
    int* counts = counts_all + c_cntoff[m];
    for (int i = threadIdx.x; i < nrows_b; i += 256)
        counts[rowlo + i] = cnt[i];
}

// ---------------- softmax over the two 4-element attention vectors ----------------
__global__ void softmax4_kernel(const float* __restrict__ adi,
                                const float* __restrict__ amv,
                                float* __restrict__ w) {
    if (blockIdx.x == 0 && threadIdx.x == 0) {
        for (int b = 0; b < 2; b++) {
            const float* a = b ? amv : adi;
            float m = a[0];
            for (int l = 1; l < 4; l++) m = fmaxf(m, a[l]);
            float e[4]; float s = 0.f;
            for (int l = 0; l < 4; l++) { e[l] = __expf(a[l] - m); s += e[l]; }
            for (int l = 0; l < 4; l++) w[b * 4 + l] = e[l] / s;
        }
    }
}

// ---------------- fp32 -> packed bf16 cast (pois) ----------------
__global__ void cast_bf16_kernel(const float* __restrict__ src, uint32* __restrict__ dst, int npairs) {
    int i = blockIdx.x * blockDim.x + threadIdx.x;
    if (i < npairs) {
        float2 f = *(const float2*)(src + (size_t)i * 2);
        dst[i] = bfPACK(f.x, f.y);
    }
}

// ---------------- hop1 SpMM: y_bf[row] = A @ x_bf, one wave/row, ELL, bf16 gather ----------------
template<int CAP>
__global__ __launch_bounds__(256) void spmm1_kernel(
    const int* __restrict__ counts, const uint32* __restrict__ ell,
    const uint32* __restrict__ xbf, uint32* __restrict__ ybf, int n_rows) {
    int row = (blockIdx.x * blockDim.x + threadIdx.x) >> 6;
    int lane = threadIdx.x & 63;
    if (row >= n_rows) return;
    int cnt = counts[row];
    // lanes >= cnt load garbage entries but they are never broadcast
    uint32 e = ell[(size_t)row * CAP + lane];
    float2 acc = make_float2(0.f, 0.f);
    int j = 0;
    for (; j + 4 <= cnt; j += 4) {
        uint32 ea = __shfl(e, j),     eb = __shfl(e, j + 1);
        uint32 ec = __shfl(e, j + 2), ed = __shfl(e, j + 3);
        uint32 ua = xbf[(size_t)csrCOL(ea) * 64 + lane];
        uint32 ub = xbf[(size_t)csrCOL(eb) * 64 + lane];
        uint32 uc = xbf[(size_t)csrCOL(ec) * 64 + lane];
        uint32 ud = xbf[(size_t)csrCOL(ed) * 64 + lane];
        float va = csrVAL(ea), vb = csrVAL(eb), vc = csrVAL(ec), vd = csrVAL(ed);
        acc.x = fmaf(va, bfLO(ua), acc.x); acc.y = fmaf(va, bfHI(ua), acc.y);
        acc.x = fmaf(vb, bfLO(ub), acc.x); acc.y = fmaf(vb, bfHI(ub), acc.y);
        acc.x = fmaf(vc, bfLO(uc), acc.x); acc.y = fmaf(vc, bfHI(uc), acc.y);
        acc.x = fmaf(vd, bfLO(ud), acc.x); acc.y = fmaf(vd, bfHI(ud), acc.y);
    }
    for (; j < cnt; j++) {
        uint32 ej = __shfl(e, j);
        uint32 u = xbf[(size_t)csrCOL(ej) * 64 + lane];
        float vj = csrVAL(ej);
        acc.x = fmaf(vj, bfLO(u), acc.x);
        acc.y = fmaf(vj, bfHI(u), acc.y);
    }
    ybf[(size_t)row * 64 + lane] = bfPACK(acc.x, acc.y);
}

// ---------------- hop2: xnew = relu(A@m)+xin, bf16 in/out, ELL ----------------
template<int CAP>
__global__ __launch_bounds__(256) void spmm2_kernel(
    const int* __restrict__ counts, const uint32* __restrict__ ell,
    const uint32* __restrict__ mbf, const uint32* __restrict__ xinbf,
    uint32* __restrict__ xoutbf, int n_rows) {
    int row = (blockIdx.x * blockDim.x + threadIdx.x) >> 6;
    int lane = threadIdx.x & 63;
    if (row >= n_rows) return;
    int cnt = counts[row];
    uint32 e = ell[(size_t)row * CAP + lane];
    float2 acc = make_float2(0.f, 0.f);
    int j = 0;
    for (; j + 4 <= cnt; j += 4) {
        uint32 ea = __shfl(e, j),     eb = __shfl(e, j + 1);
        uint32 ec = __shfl(e, j + 2), ed = __shfl(e, j + 3);
        uint32 ua = mbf[(size_t)csrCOL(ea) * 64 + lane];
        uint32 ub = mbf[(size_t)csrCOL(eb) * 64 + lane];
        uint32 uc = mbf[(size_t)csrCOL(ec) * 64 + lane];
        uint32 ud = mbf[(size_t)csrCOL(ed) * 64 + lane];
        float va = csrVAL(ea), vb = csrVAL(eb), vc = csrVAL(ec), vd = csrVAL(ed);
        acc.x = fmaf(va, bfLO(ua), acc.x); acc.y = fmaf(va, bfHI(ua), acc.y);
        acc.x = fmaf(vb, bfLO(ub), acc.x); acc.y = fmaf(vb, bfHI(ub), acc.y);
        acc.x = fmaf(vc, bfLO(uc), acc.x); acc.y = fmaf(vc, bfHI(uc), acc.y);
        acc.x = fmaf(vd, bfLO(ud), acc.x); acc.y = fmaf(vd, bfHI(ud), acc.y);
    }
    for (; j < cnt; j++) {
        uint32 ej = __shfl(e, j);
        uint32 u = mbf[(size_t)csrCOL(ej) * 64 + lane];
        float vj = csrVAL(ej);
        acc.x = fmaf(vj, bfLO(u), acc.x);
        acc.y = fmaf(vj, bfHI(u), acc.y);
    }
    size_t o32 = (size_t)row * 64 + lane;
    uint32 ui = xinbf[o32];
    float xn0 = fmaxf(acc.x, 0.f) + bfLO(ui);
    float xn1 = fmaxf(acc.y, 0.f) + bfHI(ui);
    xoutbf[o32] = bfPACK(xn0, xn1);
}

// ---------------- epilogues: out = (w0di+w0mv)*pois + sum_l w_l * x_l ----------------
__global__ void epi1_kernel(const float* __restrict__ pois,
                            const uint32* __restrict__ x1, const uint32* __restrict__ x2,
                            const uint32* __restrict__ x3, const float* __restrict__ w,
                            float* __restrict__ out) {
    int i = blockIdx.x * blockDim.x + threadIdx.x;
    if (i < NPOI * 64) {
        float w0 = w[0] + w[4];
        float2 pf = ((const float2*)pois)[i];
        uint32 u1 = x1[i], u2 = x2[i], u3 = x3[i];
        float o0 = w0 * pf.x + w[1] * bfLO(u1) + w[2] * bfLO(u2) + w[3] * bfLO(u3);
        float o1 = w0 * pf.y + w[1] * bfHI(u1) + w[2] * bfHI(u2) + w[3] * bfHI(u3);
        ((float2*)out)[i] = make_float2(o0, o1);
    }
}

__global__ void epi2_kernel(const uint32* __restrict__ x1, const uint32* __restrict__ x2,
                            const uint32* __restrict__ x3, const float* __restrict__ w,
                            float* __restrict__ out) {
    int i = blockIdx.x * blockDim.x + threadIdx.x;
    if (i < NPOI * 64) {
        uint32 u1 = x1[i], u2 = x2[i], u3 = x3[i];
        float2 ov = ((float2*)out)[i];
        ov.x += w[5] * bfLO(u1) + w[6] * bfLO(u2) + w[7] * bfLO(u3);
        ov.y += w[5] * bfHI(u1) + w[6] * bfHI(u2) + w[7] * bfHI(u3);
        ((float2*)out)[i] = ov;
    }
}

extern "C" void kernel_launch(void* const* d_in, const int* in_sizes, int n_in,
                              void* d_out, int out_size, void* d_ws, size_t ws_size,
                              hipStream_t stream) {
    const float* pois = (const float*)d_in[0];
    const int*   rows_in[4] = { (const int*)d_in[1], (const int*)d_in[4],
                                (const int*)d_in[7], (const int*)d_in[10] };
    const int*   cols_in[4] = { (const int*)d_in[2], (const int*)d_in[5],
                                (const int*)d_in[8], (const int*)d_in[11] };
    const float* vals_in[4] = { (const float*)d_in[3], (const float*)d_in[6],
                                (const float*)d_in[9], (const float*)d_in[12] };
    const float* attn_di = (const float*)d_in[13];
    const float* attn_mv = (const float*)d_in[14];
    float* out = (float*)d_out;

    const int NTOT = NEDGE + NPOI + NUSER + NPOI;  // 300000
    const int cnt_off[4] = { 0, NEDGE, NEDGE + NPOI, NEDGE + NPOI + NUSER };
    const long long ell_off[4] = { 0, 3200000, 8000000, 11200000 };

    // -------- workspace carve-up (~182 MB) --------
    char* p = (char*)d_ws;
    float*  wsoft      = (float*)p;  p += 256;
    int*    counts_all = (int*)p;    p += (size_t)NTOT * 4;
    p = (char*)(((size_t)p + 255) & ~255ull);
    int*    scanG      = (int*)p;    p += (size_t)(SCANN + 64) * 4;  // 50177 + pad
    p = (char*)(((size_t)p + 255) & ~255ull);
    uint32* ell        = (uint32*)p; p += (size_t)16000000 * 4;     // 64 MB ELL
    uint32* mbf        = (uint32*)p; p += (size_t)NEDGE * 64 * 4;   // 12.8 MB
    uint32* poisbf     = (uint32*)p; p += (size_t)NPOI * 64 * 4;    // 25.6 MB
    uint32* xl[3];
    for (int l = 0; l < 3; l++) { xl[l] = (uint32*)p; p += (size_t)NPOI * 64 * 4; }
    // records (32 MB) alias xl[0..1] (51.2 MB): consumed by fillB before spmm writes xl.
    uint2* rec = (uint2*)xl[0];
    (void)ws_size; (void)out_size; (void)n_in; (void)in_sizes;

    // -------- ELL build: hist -> scan -> scatter-sort -> bucket fill --------
    histH_kernel<<<dim3(PB, 4), 256, 0, stream>>>(
        rows_in[0], rows_in[1], rows_in[2], rows_in[3], scanG);
    scan_kernel<<<1, 256, 0, stream>>>(scanG);
    scatS_kernel<<<dim3(PB, 4), 256, 0, stream>>>(
        rows_in[0], rows_in[1], rows_in[2], rows_in[3],
        cols_in[0], cols_in[1], cols_in[2], cols_in[3],
        vals_in[0], vals_in[1], vals_in[2], vals_in[3],
        scanG, rec);
    fillB_kernel<<<4 * NBKT, 256, 0, stream>>>(scanG, rec, counts_all, ell);

    // -------- attention weights + bf16 cast of pois --------
    softmax4_kernel<<<1, 64, 0, stream>>>(attn_di, attn_mv, wsoft);
    cast_bf16_kernel<<<ceil_div(NPOI * 64, 256), 256, 0, stream>>>(pois, poisbf, NPOI * 64);

    // -------- two branches, 3 layers each; epilogue per branch --------
    for (int br = 0; br < 2; br++) {
        int m1i = br ? 2 : 0;   // up  : tar   (50k rows, CAP 64)
        int m2i = br ? 3 : 1;   // pu  : src   (100k rows, CAP 48)
        const int* cn1 = counts_all + cnt_off[m1i];
        const int* cn2 = counts_all + cnt_off[m2i];
        const uint32* el1 = ell + ell_off[m1i];
        const uint32* el2 = ell + ell_off[m2i];
        const int n1 = 50000;  // NEDGE == NUSER
        const uint32* xcur = poisbf;
        for (int l = 1; l <= NL; l++) {
            spmm1_kernel<64><<<ceil_div(n1, 4), 256, 0, stream>>>(cn1, el1, xcur, mbf, n1);
            spmm2_kernel<48><<<ceil_div(NPOI, 4), 256, 0, stream>>>(
                cn2, el2, mbf, xcur, xl[l - 1], NPOI);
            xcur = xl[l - 1];
        }
        if (br == 0)
            epi1_kernel<<<ceil_div(NPOI * 64, 256), 256, 0, stream>>>(
                pois, xl[0], xl[1], xl[2], wsoft, out);
        else
            epi2_kernel<<<ceil_div(NPOI * 64, 256), 256, 0, stream>>>(
                xl[0], xl[1], xl[2], wsoft, out);
    }
}

// Round 4
// 781.784 us; speedup vs baseline: 1.2395x; 1.0918x over previous
//
#include <hip/hip_runtime.h>

#define NNZC   1000000
#define NPOI   100000
#define NEDGE  50000
#define NUSER  50000
#define DIM    128
#define NL     3

#define PB     64          // chunks per matrix for hist/scatter passes (NNZC/PB = 15625)
#define NBKT   196         // row-buckets per matrix (rows>>shift, shift 8 or 9 -> max bucket 195)
#define SCANN  (4 * NBKT * PB)   // 50176 counters (+1 sentinel)

static inline int ceil_div(int a, int b) { return (a + b - 1) / b; }

typedef unsigned int uint32;

// ---- bf16 helpers: rows stored as packed pairs (uint32 = 2 bf16, little-endian) ----
__device__ __forceinline__ float bfLO(uint32 u) { return __uint_as_float(u << 16); }
__device__ __forceinline__ float bfHI(uint32 u) { return __uint_as_float(u & 0xffff0000u); }
__device__ __forceinline__ uint32 bf16_rne(float f) {
    uint32 u = __float_as_uint(f);
    return (u + 0x7fffu + ((u >> 16) & 1u)) >> 16;
}
__device__ __forceinline__ uint32 bfPACK(float a, float b) {
    return bf16_rne(a) | (bf16_rne(b) << 16);
}
// ---- packed ELL entry: vals uniform [0,1) -> sign bit 0 -> 15-bit bf16; col fits 17 bits.
__device__ __forceinline__ uint32 csrPACK(int col, float val) {
    return ((uint32)col) | (bf16_rne(val) << 17);
}
__device__ __forceinline__ int   csrCOL(uint32 e) { return (int)(e & 0x1FFFFu); }
__device__ __forceinline__ float csrVAL(uint32 e) { return __uint_as_float((e >> 17) << 16); }

// per-matrix constants: tar(0), src(1), up(2), pu(3)
__device__ __constant__ const int c_nrows[4]  = { NEDGE, NPOI, NUSER, NPOI };
__device__ __constant__ const int c_cntoff[4] = { 0, NEDGE, NEDGE + NPOI, NEDGE + NPOI + NUSER };
__device__ __constant__ const int c_cap[4]    = { 64, 48, 64, 48 };
__device__ __constant__ const int c_shift[4]  = { 8, 9, 8, 9 };   // rows-per-bucket 256 / 512
__device__ __constant__ const long long c_elloff[4] = { 0, 3200000, 8000000, 11200000 };
// total ELL entries = 16,000,000 (64 MB)

// =============== ELL build: bucketed counting sort (4 passes, no global atomics) ===============

// Pass H: per-(matrix, chunk) histogram over row-buckets.  histG[(m*NBKT+b)*PB + p]
// 1024 threads: 256 blocks = 1 block/CU x 16 waves (round-3 scatS showed 9% occupancy at 256 thr).
__global__ __launch_bounds__(1024) void histH_kernel(
    const int* __restrict__ r0, const int* __restrict__ r1,
    const int* __restrict__ r2, const int* __restrict__ r3,
    int* __restrict__ histG) {
    __shared__ int h[NBKT];
    int m = blockIdx.y, p = blockIdx.x;
    for (int i = threadIdx.x; i < NBKT; i += 1024) h[i] = 0;
    __syncthreads();
    const int* r = (m == 0) ? r0 : (m == 1) ? r1 : (m == 2) ? r2 : r3;
    int shift = c_shift[m];
    int lo = p * (NNZC / PB), hi = lo + NNZC / PB;
    for (int i = lo + (int)threadIdx.x; i < hi; i += 1024)
        atomicAdd(&h[r[i] >> shift], 1);
    __syncthreads();
    for (int b = threadIdx.x; b < NBKT; b += 1024)
        histG[(m * NBKT + b) * PB + p] = h[b];
}

// Pass X: in-place exclusive scan of the 50176 counters (+ sentinel total at [SCANN]).
__global__ __launch_bounds__(256) void scan_kernel(int* __restrict__ g) {
    __shared__ int base[257];
    int t = threadIdx.x;
    const int chunk = SCANN / 256;   // 196
    int lo = t * chunk;
    int s = 0;
    for (int i = 0; i < chunk; i++) s += g[lo + i];
    base[t + 1] = s;
    __syncthreads();
    if (t == 0) {
        base[0] = 0;
        for (int i = 1; i <= 256; i++) base[i] += base[i - 1];
    }
    __syncthreads();
    int off = base[t];
    for (int i = 0; i < chunk; i++) { int v = g[lo + i]; g[lo + i] = off; off += v; }
    if (t == 255) g[SCANN] = base[256];
}

// Pass S: scatter (row, packed entry) records into exclusive dense ranges (bucket-major).
// Each block owns range [scan[(m,b,p)], +hist) per bucket -> LDS cursors, no global atomics.
__global__ __launch_bounds__(1024) void scatS_kernel(
    const int* __restrict__ r0, const int* __restrict__ r1,
    const int* __restrict__ r2, const int* __restrict__ r3,
    const int* __restrict__ c0, const int* __restrict__ c1,
    const int* __restrict__ c2, const int* __restrict__ c3,
    const float* __restrict__ v0, const float* __restrict__ v1,
    const float* __restrict__ v2, const float* __restrict__ v3,
    const int* __restrict__ scanG, uint2* __restrict__ rec) {
    __shared__ int cur[NBKT];
    int m = blockIdx.y, p = blockIdx.x;
    for (int b = threadIdx.x; b < NBKT; b += 1024)
        cur[b] = scanG[(m * NBKT + b) * PB + p];
    __syncthreads();
    const int*   r = (m == 0) ? r0 : (m == 1) ? r1 : (m == 2) ? r2 : r3;
    const int*   c = (m == 0) ? c0 : (m == 1) ? c1 : (m == 2) ? c2 : c3;
    const float* v = (m == 0) ? v0 : (m == 1) ? v1 : (m == 2) ? v2 : v3;
    int shift = c_shift[m];
    int lo = p * (NNZC / PB), hi = lo + NNZC / PB;
    for (int i = lo + (int)threadIdx.x; i < hi; i += 1024) {
        int row = r[i];
        int pos = atomicAdd(&cur[row >> shift], 1);
        rec[pos] = make_uint2((uint32)row, csrPACK(c[i], v[i]));
    }
}

// Pass B: one block per (matrix, bucket).  Bucket rows are block-exclusive -> LDS row
// counters (no global atomics, no counts memset); ELL scatter confined to a 64-96 KB
// L2-resident region so lines fill before eviction.  512 thr -> ~3 blocks/CU, 24 waves.
__global__ __launch_bounds__(512) void fillB_kernel(
    const int* __restrict__ scanG, const uint2* __restrict__ rec,
    int* __restrict__ counts_all, uint32* __restrict__ ell) {
    __shared__ int cnt[512];
    int bx = (int)blockIdx.x;
    int m = bx / NBKT, b = bx - m * NBKT;
    int shift = c_shift[m];
    int rowlo = b << shift;
    int bklen = 1 << shift;
    for (int i = threadIdx.x; i < bklen; i += 512) cnt[i] = 0;
    __syncthreads();
    int lo = scanG[(m * NBKT + b) * PB];
    int hi = scanG[(m * NBKT + b + 1) * PB];   // b=195,m=3 -> scanG[SCANN] sentinel
    int cap = c_cap[m];
    uint32* ebase = ell + c_elloff[m];
    for (int i = lo + (int)threadIdx.x; i < hi; i += 512) {
        uint2 e = rec[i];
        int row = (int)e.x;
        int pos = atomicAdd(&cnt[row - rowlo], 1);
        ebase[(size_t)row * cap + pos] = e.y;
    }
    __syncthreads();
    int nrows_b = c_nrows[m] - rowlo;
    if (nrows_b > bklen) nrows_b = bklen;
    int* counts = counts_all + c_cntoff[m];
    for (int i = threadIdx.x; i < nrows_b; i += 512)
        counts[rowlo + i] = cnt[i];
}

// ---------------- softmax over the two 4-element attention vectors ----------------
__global__ void softmax4_kernel(const float* __restrict__ adi,
                                const float* __restrict__ amv,
                                float* __restrict__ w) {
    if (blockIdx.x == 0 && threadIdx.x == 0) {
        for (int b = 0; b < 2; b++) {
            const float* a = b ? amv : adi;
            float m = a[0];
            for (int l = 1; l < 4; l++) m = fmaxf(m, a[l]);
            float e[4]; float s = 0.f;
            for (int l = 0; l < 4; l++) { e[l] = __expf(a[l] - m); s += e[l]; }
            for (int l = 0; l < 4; l++) w[b * 4 + l] = e[l] / s;
        }
    }
}

// ---------------- fp32 -> packed bf16 cast (pois) ----------------
__global__ void cast_bf16_kernel(const float* __restrict__ src, uint32* __restrict__ dst, int npairs) {
    int i = blockIdx.x * blockDim.x + threadIdx.x;
    if (i < npairs) {
        float2 f = *(const float2*)(src + (size_t)i * 2);
        dst[i] = bfPACK(f.x, f.y);
    }
}

// ---- shared FMA helper for the gather loops ----
#define GFMA(EV, UV) do { float _v = csrVAL(EV); \
    acc.x = fmaf(_v, bfLO(UV), acc.x); acc.y = fmaf(_v, bfHI(UV), acc.y); } while (0)

// ---------------- hop1 SpMM: y_bf[row] = A @ x_bf, one wave/row, ELL, bf16 gather ----------------
// 8-wide main loop: 8 outstanding gathers/wave (round-3 spmm ran at 4 TB/s, VALUBusy 19%,
// occupancy ~60% -> latency-bound at 4 outstanding; if this is neutral, the path is L3-BW-bound).
template<int CAP>
__global__ __launch_bounds__(256) void spmm1_kernel(
    const int* __restrict__ counts, const uint32* __restrict__ ell,
    const uint32* __restrict__ xbf, uint32* __restrict__ ybf, int n_rows) {
    int row = (blockIdx.x * blockDim.x + threadIdx.x) >> 6;
    int lane = threadIdx.x & 63;
    if (row >= n_rows) return;
    int cnt = counts[row];
    // lanes >= cnt load garbage entries but they are never broadcast
    uint32 e = ell[(size_t)row * CAP + lane];
    float2 acc = make_float2(0.f, 0.f);
    int j = 0;
    for (; j + 8 <= cnt; j += 8) {
        uint32 e0 = __shfl(e, j),     e1 = __shfl(e, j + 1);
        uint32 e2 = __shfl(e, j + 2), e3 = __shfl(e, j + 3);
        uint32 e4 = __shfl(e, j + 4), e5 = __shfl(e, j + 5);
        uint32 e6 = __shfl(e, j + 6), e7 = __shfl(e, j + 7);
        uint32 u0 = xbf[(size_t)csrCOL(e0) * 64 + lane];
        uint32 u1 = xbf[(size_t)csrCOL(e1) * 64 + lane];
        uint32 u2 = xbf[(size_t)csrCOL(e2) * 64 + lane];
        uint32 u3 = xbf[(size_t)csrCOL(e3) * 64 + lane];
        uint32 u4 = xbf[(size_t)csrCOL(e4) * 64 + lane];
        uint32 u5 = xbf[(size_t)csrCOL(e5) * 64 + lane];
        uint32 u6 = xbf[(size_t)csrCOL(e6) * 64 + lane];
        uint32 u7 = xbf[(size_t)csrCOL(e7) * 64 + lane];
        GFMA(e0, u0); GFMA(e1, u1); GFMA(e2, u2); GFMA(e3, u3);
        GFMA(e4, u4); GFMA(e5, u5); GFMA(e6, u6); GFMA(e7, u7);
    }
    for (; j + 4 <= cnt; j += 4) {
        uint32 e0 = __shfl(e, j),     e1 = __shfl(e, j + 1);
        uint32 e2 = __shfl(e, j + 2), e3 = __shfl(e, j + 3);
        uint32 u0 = xbf[(size_t)csrCOL(e0) * 64 + lane];
        uint32 u1 = xbf[(size_t)csrCOL(e1) * 64 + lane];
        uint32 u2 = xbf[(size_t)csrCOL(e2) * 64 + lane];
        uint32 u3 = xbf[(size_t)csrCOL(e3) * 64 + lane];
        GFMA(e0, u0); GFMA(e1, u1); GFMA(e2, u2); GFMA(e3, u3);
    }
    for (; j < cnt; j++) {
        uint32 ej = __shfl(e, j);
        uint32 u = xbf[(size_t)csrCOL(ej) * 64 + lane];
        GFMA(ej, u);
    }
    ybf[(size_t)row * 64 + lane] = bfPACK(acc.x, acc.y);
}

// ---------------- hop2: xnew = relu(A@m)+xin, bf16 in/out, ELL ----------------
template<int CAP>
__global__ __launch_bounds__(256) void spmm2_kernel(
    const int* __restrict__ counts, const uint32* __restrict__ ell,
    const uint32* __restrict__ mbf, const uint32* __restrict__ xinbf,
    uint32* __restrict__ xoutbf, int n_rows) {
    int row = (blockIdx.x * blockDim.x + threadIdx.x) >> 6;
    int lane = threadIdx.x & 63;
    if (row >= n_rows) return;
    int cnt = counts[row];
    uint32 e = ell[(size_t)row * CAP + lane];
    float2 acc = make_float2(0.f, 0.f);
    int j = 0;
    for (; j + 8 <= cnt; j += 8) {
        uint32 e0 = __shfl(e, j),     e1 = __shfl(e, j + 1);
        uint32 e2 = __shfl(e, j + 2), e3 = __shfl(e, j + 3);
        uint32 e4 = __shfl(e, j + 4), e5 = __shfl(e, j + 5);
        uint32 e6 = __shfl(e, j + 6), e7 = __shfl(e, j + 7);
        uint32 u0 = mbf[(size_t)csrCOL(e0) * 64 + lane];
        uint32 u1 = mbf[(size_t)csrCOL(e1) * 64 + lane];
        uint32 u2 = mbf[(size_t)csrCOL(e2) * 64 + lane];
        uint32 u3 = mbf[(size_t)csrCOL(e3) * 64 + lane];
        uint32 u4 = mbf[(size_t)csrCOL(e4) * 64 + lane];
        uint32 u5 = mbf[(size_t)csrCOL(e5) * 64 + lane];
        uint32 u6 = mbf[(size_t)csrCOL(e6) * 64 + lane];
        uint32 u7 = mbf[(size_t)csrCOL(e7) * 64 + lane];
        GFMA(e0, u0); GFMA(e1, u1); GFMA(e2, u2); GFMA(e3, u3);
        GFMA(e4, u4); GFMA(e5, u5); GFMA(e6, u6); GFMA(e7, u7);
    }
    for (; j + 4 <= cnt; j += 4) {
        uint32 e0 = __shfl(e, j),     e1 = __shfl(e, j + 1);
        uint32 e2 = __shfl(e, j + 2), e3 = __shfl(e, j + 3);
        uint32 u0 = mbf[(size_t)csrCOL(e0) * 64 + lane];
        uint32 u1 = mbf[(size_t)csrCOL(e1) * 64 + lane];
        uint32 u2 = mbf[(size_t)csrCOL(e2) * 64 + lane];
        uint32 u3 = mbf[(size_t)csrCOL(e3) * 64 + lane];
        GFMA(e0, u0); GFMA(e1, u1); GFMA(e2, u2); GFMA(e3, u3);
    }
    for (; j < cnt; j++) {
        uint32 ej = __shfl(e, j);
        uint32 u = mbf[(size_t)csrCOL(ej) * 64 + lane];
        GFMA(ej, u);
    }
    size_t o32 = (size_t)row * 64 + lane;
    uint32 ui = xinbf[o32];
    float xn0 = fmaxf(acc.x, 0.f) + bfLO(ui);
    float xn1 = fmaxf(acc.y, 0.f) + bfHI(ui);
    xoutbf[o32] = bfPACK(xn0, xn1);
}

// ---------------- epilogues: out = (w0di+w0mv)*pois + sum_l w_l * x_l ----------------
__global__ void epi1_kernel(const float* __restrict__ pois,
                            const uint32* __restrict__ x1, const uint32* __restrict__ x2,
                            const uint32* __restrict__ x3, const float* __restrict__ w,
                            float* __restrict__ out) {
    int i = blockIdx.x * blockDim.x + threadIdx.x;
    if (i < NPOI * 64) {
        float w0 = w[0] + w[4];
        float2 pf = ((const float2*)pois)[i];
        uint32 u1 = x1[i], u2 = x2[i], u3 = x3[i];
        float o0 = w0 * pf.x + w[1] * bfLO(u1) + w[2] * bfLO(u2) + w[3] * bfLO(u3);
        float o1 = w0 * pf.y + w[1] * bfHI(u1) + w[2] * bfHI(u2) + w[3] * bfHI(u3);
        ((float2*)out)[i] = make_float2(o0, o1);
    }
}

__global__ void epi2_kernel(const uint32* __restrict__ x1, const uint32* __restrict__ x2,
                            const uint32* __restrict__ x3, const float* __restrict__ w,
                            float* __restrict__ out) {
    int i = blockIdx.x * blockDim.x + threadIdx.x;
    if (i < NPOI * 64) {
        uint32 u1 = x1[i], u2 = x2[i], u3 = x3[i];
        float2 ov = ((float2*)out)[i];
        ov.x += w[5] * bfLO(u1) + w[6] * bfLO(u2) + w[7] * bfLO(u3);
        ov.y += w[5] * bfHI(u1) + w[6] * bfHI(u2) + w[7] * bfHI(u3);
        ((float2*)out)[i] = ov;
    }
}

extern "C" void kernel_launch(void* const* d_in, const int* in_sizes, int n_in,
                              void* d_out, int out_size, void* d_ws, size_t ws_size,
                              hipStream_t stream) {
    const float* pois = (const float*)d_in[0];
    const int*   rows_in[4] = { (const int*)d_in[1], (const int*)d_in[4],
                                (const int*)d_in[7], (const int*)d_in[10] };
    const int*   cols_in[4] = { (const int*)d_in[2], (const int*)d_in[5],
                                (const int*)d_in[8], (const int*)d_in[11] };
    const float* vals_in[4] = { (const float*)d_in[3], (const float*)d_in[6],
                                (const float*)d_in[9], (const float*)d_in[12] };
    const float* attn_di = (const float*)d_in[13];
    const float* attn_mv = (const float*)d_in[14];
    float* out = (float*)d_out;

    const int NTOT = NEDGE + NPOI + NUSER + NPOI;  // 300000
    const int cnt_off[4] = { 0, NEDGE, NEDGE + NPOI, NEDGE + NPOI + NUSER };
    const long long ell_off[4] = { 0, 3200000, 8000000, 11200000 };

    // -------- workspace carve-up (~182 MB) --------
    char* p = (char*)d_ws;
    float*  wsoft      = (float*)p;  p += 256;
    int*    counts_all = (int*)p;    p += (size_t)NTOT * 4;
    p = (char*)(((size_t)p + 255) & ~255ull);
    int*    scanG      = (int*)p;    p += (size_t)(SCANN + 64) * 4;  // 50177 + pad
    p = (char*)(((size_t)p + 255) & ~255ull);
    uint32* ell        = (uint32*)p; p += (size_t)16000000 * 4;     // 64 MB ELL
    uint32* mbf        = (uint32*)p; p += (size_t)NEDGE * 64 * 4;   // 12.8 MB
    uint32* poisbf     = (uint32*)p; p += (size_t)NPOI * 64 * 4;    // 25.6 MB
    uint32* xl[3];
    for (int l = 0; l < 3; l++) { xl[l] = (uint32*)p; p += (size_t)NPOI * 64 * 4; }
    // records (32 MB) alias xl[0..1] (51.2 MB): consumed by fillB before spmm writes xl.
    uint2* rec = (uint2*)xl[0];
    (void)ws_size; (void)out_size; (void)n_in; (void)in_sizes;

    // -------- ELL build: hist -> scan -> scatter-sort -> bucket fill --------
    histH_kernel<<<dim3(PB, 4), 1024, 0, stream>>>(
        rows_in[0], rows_in[1], rows_in[2], rows_in[3], scanG);
    scan_kernel<<<1, 256, 0, stream>>>(scanG);
    scatS_kernel<<<dim3(PB, 4), 1024, 0, stream>>>(
        rows_in[0], rows_in[1], rows_in[2], rows_in[3],
        cols_in[0], cols_in[1], cols_in[2], cols_in[3],
        vals_in[0], vals_in[1], vals_in[2], vals_in[3],
        scanG, rec);
    fillB_kernel<<<4 * NBKT, 512, 0, stream>>>(scanG, rec, counts_all, ell);

    // -------- attention weights + bf16 cast of pois --------
    softmax4_kernel<<<1, 64, 0, stream>>>(attn_di, attn_mv, wsoft);
    cast_bf16_kernel<<<ceil_div(NPOI * 64, 256), 256, 0, stream>>>(pois, poisbf, NPOI * 64);

    // -------- two branches, 3 layers each; epilogue per branch --------
    for (int br = 0; br < 2; br++) {
        int m1i = br ? 2 : 0;   // up  : tar   (50k rows, CAP 64)
        int m2i = br ? 3 : 1;   // pu  : src   (100k rows, CAP 48)
        const int* cn1 = counts_all + cnt_off[m1i];
        const int* cn2 = counts_all + cnt_off[m2i];
        const uint32* el1 = ell + ell_off[m1i];
        const uint32* el2 = ell + ell_off[m2i];
        const int n1 = 50000;  // NEDGE == NUSER
        const uint32* xcur = poisbf;
        for (int l = 1; l <= NL; l++) {
            spmm1_kernel<64><<<ceil_div(n1, 4), 256, 0, stream>>>(cn1, el1, xcur, mbf, n1);
            spmm2_kernel<48><<<ceil_div(NPOI, 4), 256, 0, stream>>>(
                cn2, el2, mbf, xcur, xl[l - 1], NPOI);
            xcur = xl[l - 1];
        }
        if (br == 0)
            epi1_kernel<<<ceil_div(NPOI * 64, 256), 256, 0, stream>>>(
                pois, xl[0], xl[1], xl[2], wsoft, out);
        else
            epi2_kernel<<<ceil_div(NPOI * 64, 256), 256, 0, stream>>>(
                xl[0], xl[1], xl[2], wsoft, out);
    }
}